// Round 9
// baseline (272.951 us; speedup 1.0000x reference)
//
#include <hip/hip_runtime.h>
#include <hip/hip_bf16.h>

typedef __attribute__((ext_vector_type(8))) short bf16x8;
typedef __attribute__((ext_vector_type(4))) float f32x4;
typedef __attribute__((ext_vector_type(4))) unsigned int u32x4;

#define CIN 64
#define COUT 64
#define NK 64
#define EPSV 1e-5f
#define ENC_NEG_INF 0x007FFFFFu
#define BKT 98               // coarse buckets = ceil(50000/512)
#define CAP 9728             // records per bucket (mean 8163)
#define TROW 1040            // padded LDS row bytes (1024 + 16)
#define NSLOT 256            // BN partial-sum spread slots (256 x 128 floats)

__device__ __forceinline__ unsigned encf(float f) {
    unsigned b = __float_as_uint(f);
    return (b & 0x80000000u) ? ~b : (b | 0x80000000u);
}
__device__ __forceinline__ float decf(unsigned u) {
    unsigned b = (u & 0x80000000u) ? (u & 0x7FFFFFFFu) : ~u;
    return __uint_as_float(b);
}
__device__ __forceinline__ unsigned pack2bf(float a, float b) {
    unsigned ua = (unsigned)__bfloat16_as_ushort(__float2bfloat16(a));
    unsigned ub = (unsigned)__bfloat16_as_ushort(__float2bfloat16(b));
    return ua | (ub << 16);
}

// ---------------------------------------------------------------------------
// Kernel 1: fused prep + binA.
// RACE LESSON (round 5): gcnt is consumed by binA blocks IN THIS LAUNCH ->
// zeroed by hipMemsetAsync BEFORE this launch. gpart is consumed only by
// LATER launches, so zeroing it in-grid is safe.
// FENCE LESSON (round 6): no per-block __threadfence tickets on CDNA4.
// rec: x = src(16) | l0<<16 | l1<<18 | l2<<20 | q2<<22
//      y = q0 (10) | q1<<10 (10) | lslot<<20 (9; lslot = dst&511)
// ---------------------------------------------------------------------------
__global__ __launch_bounds__(256) void prep_kernel(
    const float* __restrict__ w, __hip_bfloat16* __restrict__ swz,
    const float* __restrict__ root, __hip_bfloat16* __restrict__ rt,
    const float* __restrict__ x, __hip_bfloat16* __restrict__ xb,
    unsigned* __restrict__ out, int outTotal,
    int* __restrict__ gcnt, float* __restrict__ gpart,
    const int* __restrict__ ei, const float* __restrict__ ea,
    uint2* __restrict__ cbuf, int E,
    int xTotal, int nbCvt, int nbOut4) {
    __shared__ int cnt[BKT];
    __shared__ int gbase[BKT];
    int b = blockIdx.x;
    int tid = threadIdx.x;
    if (b < 1024) {                        // swizzle_w: 262144 elems
        int i = b * 256 + tid;
        int k  = i >> 12;
        int r  = i & 4095;
        int ni = r >> 10;
        int ks = (r >> 9) & 1;
        int lane = (r >> 3) & 63;
        int j  = r & 7;
        int quad = lane >> 4, l16 = lane & 15;
        int c = ks * 32 + quad * 8 + j;
        int d = ni * 16 + l16;
        swz[i] = __float2bfloat16(w[(k << 12) + (c << 6) + d]);
        return;
    }
    b -= 1024;
    if (b < 16) {                          // swizzle_root: 4096 elems
        int r = b * 256 + tid;
        int ni = r >> 10;
        int ks = (r >> 9) & 1;
        int lane = (r >> 3) & 63;
        int j  = r & 7;
        int quad = lane >> 4, l16 = lane & 15;
        int c = ks * 32 + quad * 8 + j;
        int d = ni * 16 + l16;
        rt[r] = __float2bfloat16(root[(c << 6) + d]);
        return;
    }
    b -= 16;
    if (b < nbCvt) {                       // cvtx: fp32 -> bf16, 8/thread
        int i = (b * 256 + tid) * 8;
        if (i < xTotal) {
            float4 a = *(const float4*)&x[i];
            float4 c = *(const float4*)&x[i + 4];
            uint4 v;
            v.x = pack2bf(a.x, a.y);
            v.y = pack2bf(a.z, a.w);
            v.z = pack2bf(c.x, c.y);
            v.w = pack2bf(c.z, c.w);
            *(uint4*)&xb[i] = v;
        }
        return;
    }
    b -= nbCvt;
    if (b < nbOut4) {                      // initpool, vectorized
        int i = (b * 256 + tid) * 4;
        if (i < outTotal) {
            u32x4 v = {ENC_NEG_INF, ENC_NEG_INF, ENC_NEG_INF, ENC_NEG_INF};
            *(u32x4*)&out[i] = v;
        }
        return;
    }
    b -= nbOut4;
    if (b < (NSLOT * 128) / 256) {         // zero gpart (256*128 floats)
        gpart[b * 256 + tid] = 0.f;
        return;
    }
    b -= (NSLOT * 128) / 256;

    // ---------------- binA (block index b in [0, nbBinA)) ----------------
    if (tid < BKT) cnt[tid] = 0;
    __syncthreads();
    int base = b * 1024 + tid;
    uint2 rr[4]; int bkt4[4], rnk[4]; bool val[4];
#pragma unroll
    for (int i = 0; i < 4; ++i) {
        int e = base + i * 256;
        val[i] = e < E;
        bkt4[i] = 0; rnk[i] = 0;
        if (!val[i]) continue;
        int src = ei[e], dst = ei[E + e];
        float f0 = ea[e * 3 + 0] * 3.f;
        float f1 = ea[e * 3 + 1] * 3.f;
        float f2 = ea[e * 3 + 2] * 3.f;
        float l0 = fminf(fmaxf(floorf(f0), 0.f), 2.f);
        float l1 = fminf(fmaxf(floorf(f1), 0.f), 2.f);
        float l2 = fminf(fmaxf(floorf(f2), 0.f), 2.f);
        unsigned q0 = (unsigned)((f0 - l0) * 1024.f);
        unsigned q1 = (unsigned)((f1 - l1) * 1024.f);
        unsigned q2 = (unsigned)((f2 - l2) * 1024.f);
        int bb = dst >> 9;
        rr[i].x = (unsigned)src | ((unsigned)(int)l0 << 16) |
                  ((unsigned)(int)l1 << 18) | ((unsigned)(int)l2 << 20) | (q2 << 22);
        rr[i].y = q0 | (q1 << 10) | ((unsigned)(dst & 511) << 20);
        bkt4[i] = bb;
        rnk[i] = atomicAdd(&cnt[bb], 1);
    }
    __syncthreads();
    if (tid < BKT) gbase[tid] = cnt[tid] ? atomicAdd(&gcnt[tid], cnt[tid]) : 0;
    __syncthreads();
#pragma unroll
    for (int i = 0; i < 4; ++i) {
        if (!val[i]) continue;
        int pos = gbase[bkt4[i]] + rnk[i];
        if (pos < CAP) cbuf[(size_t)bkt4[i] * CAP + pos] = rr[i];
    }
}

// ---------------------------------------------------------------------------
// Kernel 2: fused binB + root-GEMM + xw-GEMM.
// SCHEDULING LESSON (round 7): with 33.3-KB LDS, only 4 blocks/CU fit (=1024
// co-resident). Short blocks must come FIRST in the grid — if the long GEMM
// blocks occupy the machine, binB/root serialize at the end (~25-30 us).
//   blocks [0, BKT):            binB — per-bucket dst sort -> CSR
//   blocks [BKT, BKT+nbRoot):   xroot = x @ root -> X buffer (fp32)
//   blocks [.., +1024):         full-channel xw GEMM, kz-plane blocks,
//                               node-major fp8 out, NT 32-KB coop stores
// ---------------------------------------------------------------------------
__global__ __launch_bounds__(256) void gb_kernel(
    const __hip_bfloat16* __restrict__ xb, const __hip_bfloat16* __restrict__ wswz,
    unsigned char* __restrict__ xwc8, int nNodes,
    const uint2* __restrict__ cbuf, const int* __restrict__ gcnt,
    uint2* __restrict__ rec, int* __restrict__ grpoff,
    const __hip_bfloat16* __restrict__ rt, float* __restrict__ X,
    int nbRoot) {
    __shared__ __attribute__((aligned(16))) unsigned char SM[32 * TROW]; // 33.3 KB
    __shared__ int obase_s;

    const int bid = blockIdx.x;
    const int tid = threadIdx.x;

    if (bid < BKT) {
        // ---------------- binB (LDS aliased into SM) ----------------
        int* scnt = (int*)SM;                 // 512 ints
        int* part = (int*)(SM + 2048);        // 256 ints
        const int bkt = bid;

        part[tid] = (tid < bkt) ? gcnt[tid] : 0;
        __syncthreads();
        for (int st = 128; st > 0; st >>= 1) {
            if (tid < st) part[tid] += part[tid + st];
            __syncthreads();
        }
        if (tid == 0) obase_s = part[0];
        __syncthreads();
        int out_base = obase_s;
        int nrec = min(gcnt[bkt], CAP);

        scnt[tid] = 0;
        scnt[256 + tid] = 0;
        __syncthreads();

        const uint2* cb = cbuf + (size_t)bkt * CAP;
        for (int r = tid; r < nrec; r += 256) {
            int lslot = (int)(cb[r].y >> 20) & 511;
            atomicAdd(&scnt[lslot], 1);
        }
        __syncthreads();
        {
            int b2 = tid * 2, s = 0;
#pragma unroll
            for (int i = 0; i < 2; ++i) { int v = scnt[b2 + i]; scnt[b2 + i] = s; s += v; }
            part[tid] = s;
            __syncthreads();
            for (int st = 1; st < 256; st <<= 1) {
                int t2 = (tid >= st) ? part[tid - st] : 0;
                __syncthreads();
                part[tid] += t2;
                __syncthreads();
            }
            int add = (tid == 0) ? 0 : part[tid - 1];
#pragma unroll
            for (int i = 0; i < 2; ++i) scnt[b2 + i] += add;
            __syncthreads();
        }
        int d0 = bkt << 9;
        for (int i = tid; i < 512; i += 256) {
            int d = d0 + i;
            if (d < nNodes) grpoff[d] = out_base + scnt[i];
        }
        if (bkt == BKT - 1 && tid == 0) grpoff[nNodes] = out_base + nrec;
        __syncthreads();
        for (int r = tid; r < nrec; r += 256) {
            uint2 v = cb[r];
            int lslot = (int)(v.y >> 20) & 511;
            int pos = atomicAdd(&scnt[lslot], 1);
            rec[out_base + pos] = v;
        }
        return;
    }

    if (bid < BKT + nbRoot) {
        // ---------------- root GEMM -> X ----------------
        const int rb   = bid - BKT;
        const int wave = tid >> 6, lane = tid & 63;
        const int quad = lane >> 4, l16 = lane & 15;
        const int node = rb * 64 + wave * 16 + l16;
        const bool valid = node < nNodes;

        bf16x8 bf0 = {}, bf1 = {};
        if (valid) {
            const __hip_bfloat16* xp = xb + (size_t)node * CIN + quad * 8;
            bf0 = *(const bf16x8*)(xp);
            bf1 = *(const bf16x8*)(xp + 32);
        }
#pragma unroll
        for (int ni = 0; ni < 4; ++ni) {
            f32x4 acc = {};
            bf16x8 a0 = *(const bf16x8*)&rt[ni * 1024 + 0 * 512 + lane * 8];
            bf16x8 a1 = *(const bf16x8*)&rt[ni * 1024 + 1 * 512 + lane * 8];
            acc = __builtin_amdgcn_mfma_f32_16x16x32_bf16(a0, bf0, acc, 0, 0, 0);
            acc = __builtin_amdgcn_mfma_f32_16x16x32_bf16(a1, bf1, acc, 0, 0, 0);
            if (valid)
                *(f32x4*)&X[(size_t)node * 64 + ni * 16 + quad * 4] = acc;
        }
        return;
    }

    // ---------------- xw GEMM ----------------
    const int gbid = bid - BKT - nbRoot;
    unsigned char* T = SM;
    const int wave = tid >> 6, lane = tid & 63;
    const int quad = lane >> 4, l16 = lane & 15;
    const int kz   = gbid & 3;            // 0..3

    const int tilesTotal = (nNodes + 15) >> 4;
    const int pairsTotal = (tilesTotal + 1) >> 1;

    for (int tp = gbid >> 2; tp < pairsTotal; tp += 256) {
        bf16x8 bf[2][2];
        bf[0][0] = bf16x8{}; bf[0][1] = bf16x8{};
        bf[1][0] = bf16x8{}; bf[1][1] = bf16x8{};
        int nodeA = tp * 32 + l16;
        int nodeB = tp * 32 + 16 + l16;
        if (nodeA < nNodes) {
            const __hip_bfloat16* xp = xb + (size_t)nodeA * CIN + quad * 8;
            bf[0][0] = *(const bf16x8*)(xp);
            bf[0][1] = *(const bf16x8*)(xp + 32);
        }
        if (nodeB < nNodes) {
            const __hip_bfloat16* xp = xb + (size_t)nodeB * CIN + quad * 8;
            bf[1][0] = *(const bf16x8*)(xp);
            bf[1][1] = *(const bf16x8*)(xp + 32);
        }

        for (int k2 = 0; k2 < 4; ++k2) {
            int kloc = (wave << 2) + k2;           // 0..15 within kz-plane
            const __hip_bfloat16* wg = wswz + (size_t)((kz << 4) + kloc) * 4096;
            bf16x8 wf[4][2];
#pragma unroll
            for (int ni = 0; ni < 4; ++ni)
#pragma unroll
                for (int ks = 0; ks < 2; ++ks)
                    wf[ni][ks] = *(const bf16x8*)&wg[ni * 1024 + ks * 512 + lane * 8];
            int xoff = kloc * 64;
#pragma unroll
            for (int t = 0; t < 2; ++t) {
#pragma unroll
                for (int ni = 0; ni < 4; ++ni) {
                    f32x4 acc = {};
                    acc = __builtin_amdgcn_mfma_f32_16x16x32_bf16(wf[ni][0], bf[t][0], acc, 0, 0, 0);
                    acc = __builtin_amdgcn_mfma_f32_16x16x32_bf16(wf[ni][1], bf[t][1], acc, 0, 0, 0);
                    int pk = __builtin_amdgcn_cvt_pk_fp8_f32(acc[0], acc[1], 0, false);
                    pk = __builtin_amdgcn_cvt_pk_fp8_f32(acc[2], acc[3], pk, true);
                    *(unsigned*)&T[(t * 16 + l16) * TROW + xoff + ni * 16 + quad * 4] =
                        (unsigned)pk;
                }
            }
        }
        __syncthreads();
        // NT cooperative store: 32 nodes x 1024 B (keep write stream out of L2)
        int base = tp * 32;
#pragma unroll
        for (int i = 0; i < 8; ++i) {
            int u = i * 256 + tid;          // 16-B unit, 2048 total
            int n = u >> 6, off = u & 63;
            int gn = base + n;
            if (gn < nNodes) {
                u32x4 v = *(const u32x4*)&T[n * TROW + off * 16];
                __builtin_nontemporal_store(
                    v, (u32x4*)&xwc8[(size_t)gn * 4096 + (size_t)kz * 1024 + off * 16]);
            }
        }
        __syncthreads();
    }
}

// ---------------------------------------------------------------------------
// Kernel 3: per-dst aggregation + fused node math. One wave per dst;
// lane = channel. h = elu(acc/deg + xroot + bias) written in place to X.
// BN sums: NO LDS, NO __syncthreads — each wave atomically adds its 128
// partials into a 256-way line-spread gpart (6.4M atomics over 2048 lines
// ~ 3.1K/line, hidden under the gather; round-3 lesson: >=512 lines).
// Waves retire independently -> Poisson-degree stragglers don't hold a
// block's other waves (round-7 straggler diagnosis).
// ---------------------------------------------------------------------------
__global__ __launch_bounds__(256) void agg_kernel(
    const uint2* __restrict__ rec, const int* __restrict__ grpoff,
    const unsigned char* __restrict__ xwc8, float* __restrict__ X,
    const float* __restrict__ bias, float* __restrict__ gpart,
    int nNodes) {
    int tid  = threadIdx.x;
    int gwav = (blockIdx.x * 256 + tid) >> 6;   // global wave id = dst
    int dst  = gwav;
    int lane = tid & 63;
    if (dst >= nNodes) return;

    int lo = __builtin_amdgcn_readfirstlane(grpoff[dst]);
    int hi = __builtin_amdgcn_readfirstlane(grpoff[dst + 1]);

    const float qs = 1.f / 1024.f;
    float acc = 0.f;

    auto corners = [&](uint2 r) {
        int src = (int)(r.x & 0xffffu);
        int l0  = (int)((r.x >> 16) & 3u);
        int l1  = (int)((r.x >> 18) & 3u);
        int l2  = (int)((r.x >> 20) & 3u);
        const unsigned char* p0 =
            xwc8 + (size_t)src * 4096 + l2 * 1024 + (l0 + 4 * l1) * 64 + lane;
        const unsigned char* p1 = p0 + 1024;
        float a00 = __builtin_amdgcn_cvt_f32_fp8((int)p0[0], 0);
        float a10 = __builtin_amdgcn_cvt_f32_fp8((int)p0[64], 0);
        float a01 = __builtin_amdgcn_cvt_f32_fp8((int)p0[256], 0);
        float a11 = __builtin_amdgcn_cvt_f32_fp8((int)p0[320], 0);
        float b00 = __builtin_amdgcn_cvt_f32_fp8((int)p1[0], 0);
        float b10 = __builtin_amdgcn_cvt_f32_fp8((int)p1[64], 0);
        float b01 = __builtin_amdgcn_cvt_f32_fp8((int)p1[256], 0);
        float b11 = __builtin_amdgcn_cvt_f32_fp8((int)p1[320], 0);
        float t0 = (float)(r.y & 1023u) * qs;
        float t1 = (float)((r.y >> 10) & 1023u) * qs;
        float t2 = (float)((r.x >> 22) & 1023u) * qs;
        float u0 = 1.f - t0, u1 = 1.f - t1;
        float w00 = u0 * u1, w10 = t0 * u1, w01 = u0 * t1, w11 = t0 * t1;
        float m0 = w00 * a00 + w10 * a10 + w01 * a01 + w11 * a11;
        float m1 = w00 * b00 + w10 * b10 + w01 * b01 + w11 * b11;
        acc += (1.f - t2) * m0 + t2 * m1;
    };

    int j = lo;
    for (; j + 3 < hi; j += 4) {
        uint2 r0 = rec[j];
        uint2 r1 = rec[j + 1];
        uint2 r2 = rec[j + 2];
        uint2 r3 = rec[j + 3];
        corners(r0);
        corners(r1);
        corners(r2);
        corners(r3);
    }
    for (; j < hi; ++j) corners(rec[j]);

    // fused node math
    float deg = fmaxf((float)(hi - lo), 1.f);
    size_t idx = (size_t)dst * COUT + lane;
    float pre = acc / deg + X[idx] + bias[lane];
    float hv = pre > 0.f ? pre : expm1f(pre);
    X[idx] = hv;

    float* gp = gpart + (size_t)(gwav & (NSLOT - 1)) * 128;
    atomicAdd(&gp[lane], hv);
    atomicAdd(&gp[64 + lane], hv * hv);
}

// ---------------------------------------------------------------------------
// Kernel 4: fold 256 BN partial slots; emit scale/shift for pool.
// ---------------------------------------------------------------------------
__global__ void stats_kernel(const float* __restrict__ gpart,
                             const float* __restrict__ gamma,
                             const float* __restrict__ beta,
                             float* __restrict__ gstat, int nNodes) {
    __shared__ float sv[128];
    int d = threadIdx.x;                   // 0..127
    float s = 0.f;
    for (int i = 0; i < NSLOT; ++i) s += gpart[i * 128 + d];
    sv[d] = s;
    __syncthreads();
    if (d < 64) {
        float invn = 1.f / (float)nNodes;
        float mean = sv[d] * invn;
        float var  = sv[64 + d] * invn - mean * mean;
        float sc   = gamma[d] * rsqrtf(var + EPSV);
        gstat[d]      = sc;
        gstat[64 + d] = beta[d] - mean * sc;
    }
}

// ---------------------------------------------------------------------------
// Kernel 5: voxel max-pool with precomputed BN scale/shift.
// ---------------------------------------------------------------------------
__global__ __launch_bounds__(256) void pool_kernel(
    const float* __restrict__ h, const float* __restrict__ pos,
    const int* __restrict__ batch, const float* __restrict__ gstat,
    unsigned* __restrict__ out, int nNodes) {
    int gid = blockIdx.x * 256 + threadIdx.x;
    int n = gid >> 6, d = gid & 63;
    if (n >= nNodes) return;
    float v = h[gid] * gstat[d] + gstat[64 + d];
    int v0 = min(max((int)floorf(pos[n * 3 + 0] * (1.f / 32.f)), 0), 7);
    int v1 = min(max((int)floorf(pos[n * 3 + 1] * (1.f / 32.f)), 0), 7);
    int v2 = min(max((int)floorf(pos[n * 3 + 2] * (1.f / 32.f)), 0), 7);
    int cl = batch[n] * 512 + v0 * 64 + v1 * 8 + v2;
    atomicMax(&out[cl * 64 + d], encf(v));
}

__global__ __launch_bounds__(256) void decode_kernel(unsigned* __restrict__ out, int total) {
    int i = blockIdx.x * 256 + threadIdx.x;
    if (i >= total) return;
    float f = decf(out[i]);
    if (!isfinite(f)) f = 0.f;
    ((float*)out)[i] = f;
}

// ---------------------------------------------------------------------------
extern "C" void kernel_launch(void* const* d_in, const int* in_sizes, int n_in,
                              void* d_out, int out_size, void* d_ws, size_t ws_size,
                              hipStream_t stream) {
    const float* x     = (const float*)d_in[0];
    const int*   ei    = (const int*)d_in[1];
    const float* ea    = (const float*)d_in[2];
    const float* pos   = (const float*)d_in[3];
    const int*   batch = (const int*)d_in[4];
    const float* w     = (const float*)d_in[5];
    const float* root  = (const float*)d_in[6];
    const float* bias  = (const float*)d_in[7];
    const float* gamma = (const float*)d_in[8];
    const float* beta  = (const float*)d_in[9];

    const int N = in_sizes[0] / CIN;     // 50000
    const int E = in_sizes[1] / 2;       // 800000

    // workspace carve-up (~239 MB); X holds xroot then h in place
    char* ws = (char*)d_ws;
    size_t off_b = 0;
    auto carve = [&](size_t bytes) -> char* {
        char* p = ws + off_b;
        off_b = (off_b + bytes + 255) & ~(size_t)255;
        return p;
    };
    unsigned char*  xwc8   = (unsigned char*)carve((size_t)N * NK * COUT);    // 204.8 MB
    __hip_bfloat16* wt     = (__hip_bfloat16*)carve((size_t)(NK + 1) * CIN * COUT * 2);
    __hip_bfloat16* xb     = (__hip_bfloat16*)carve((size_t)N * CIN * 2);     // 6.4 MB
    float*          X      = (float*)carve((size_t)N * COUT * 4);             // 12.8 MB
    int*            grpoff = (int*)carve((size_t)(N + 1) * 4);
    int*            gcnt   = (int*)carve(BKT * 4);
    uint2*          cbuf   = (uint2*)carve((size_t)BKT * CAP * 8);            // 7.6 MB
    uint2*          rec    = (uint2*)carve((size_t)E * 8);                    // 6.4 MB
    float*          gst    = (float*)carve(256 * 4);
    float*          gpart  = (float*)carve((size_t)NSLOT * 128 * 4);          // 128 KB
    __hip_bfloat16* rt     = wt + (size_t)NK * CIN * COUT;

    // 0: stream-ordered zeroing of counters consumed WITHIN the next launch
    hipMemsetAsync(gcnt, 0, BKT * 4, stream);

    // 1: fused prep (swizzles + cvtx + pool-init + gpart zero) + binA
    const int nbCvt  = (N * CIN / 8 + 255) / 256;
    const int nbOut4 = (out_size / 4 + 255) / 256;
    const int nbBinA = (E + 1023) / 1024;
    const int nbGpz  = (NSLOT * 128) / 256;
    prep_kernel<<<1024 + 16 + nbCvt + nbOut4 + nbGpz + nbBinA, 256, 0, stream>>>(
        w, wt, root, rt, x, xb, (unsigned*)d_out, out_size, gcnt, gpart,
        ei, ea, cbuf, E, N * CIN, nbCvt, nbOut4);

    // 2: fused binB + root-GEMM + xw-GEMM (short blocks FIRST — round-7 lesson)
    const int nbRoot = (N + 63) / 64;
    gb_kernel<<<BKT + nbRoot + 1024, 256, 0, stream>>>(
        xb, wt, xwc8, N, cbuf, gcnt, rec, grpoff, rt, X, nbRoot);

    // 3: per-dst aggregation + fused ELU + per-wave line-spread BN partials
    const int agrid = (N * 64 + 255) / 256;
    agg_kernel<<<agrid, 256, 0, stream>>>(
        rec, grpoff, xwc8, X, bias, gpart, N);

    // 4: fold BN partials -> scale/shift
    stats_kernel<<<1, 128, 0, stream>>>(gpart, gamma, beta, gst, N);

    // 5: BN affine + voxel max-pool
    pool_kernel<<<((size_t)N * COUT + 255) / 256, 256, 0, stream>>>(
        X, pos, batch, gst, (unsigned*)d_out, N);

    // 6: decode sortable-uint -> float
    decode_kernel<<<(out_size + 255) / 256, 256, 0, stream>>>((unsigned*)d_out, out_size);
}

// Round 10
// 267.180 us; speedup vs baseline: 1.0216x; 1.0216x over previous
//
#include <hip/hip_runtime.h>
#include <hip/hip_bf16.h>

typedef __attribute__((ext_vector_type(8))) short bf16x8;
typedef __attribute__((ext_vector_type(4))) float f32x4;
typedef __attribute__((ext_vector_type(4))) unsigned int u32x4;

#define CIN 64
#define COUT 64
#define NK 64
#define EPSV 1e-5f
#define ENC_NEG_INF 0x007FFFFFu
#define BKT 98               // coarse buckets = ceil(50000/512)
#define CAP 9728             // records per bucket (mean 8163)
#define TROW 1040            // padded LDS row bytes (1024 + 16)
#define NSLOT 64             // BN partial-sum spread slots (64 x 128 floats)

__device__ __forceinline__ unsigned encf(float f) {
    unsigned b = __float_as_uint(f);
    return (b & 0x80000000u) ? ~b : (b | 0x80000000u);
}
__device__ __forceinline__ float decf(unsigned u) {
    unsigned b = (u & 0x80000000u) ? (u & 0x7FFFFFFFu) : ~u;
    return __uint_as_float(b);
}
__device__ __forceinline__ unsigned pack2bf(float a, float b) {
    unsigned ua = (unsigned)__bfloat16_as_ushort(__float2bfloat16(a));
    unsigned ub = (unsigned)__bfloat16_as_ushort(__float2bfloat16(b));
    return ua | (ub << 16);
}

// ---------------------------------------------------------------------------
// Kernel 1: fused prep + binA.
// RACE LESSON (round 5): gcnt is consumed by binA blocks IN THIS LAUNCH ->
// zeroed by hipMemsetAsync BEFORE this launch. gpart is consumed only by
// LATER launches, so zeroing it in-grid is safe.
// FENCE LESSON (round 6): no per-block __threadfence tickets on CDNA4.
// ATOMIC LESSON (round 9): device atomics write through toward HBM — use
// per-block LDS reduction first (1.6M atomics, not 6.4M).
// rec: x = src(16) | l0<<16 | l1<<18 | l2<<20 | q2<<22
//      y = q0 (10) | q1<<10 (10) | lslot<<20 (9; lslot = dst&511)
// ---------------------------------------------------------------------------
__global__ __launch_bounds__(256) void prep_kernel(
    const float* __restrict__ w, __hip_bfloat16* __restrict__ swz,
    const float* __restrict__ root, __hip_bfloat16* __restrict__ rt,
    const float* __restrict__ x, __hip_bfloat16* __restrict__ xb,
    unsigned* __restrict__ out, int outTotal,
    int* __restrict__ gcnt, float* __restrict__ gpart,
    const int* __restrict__ ei, const float* __restrict__ ea,
    uint2* __restrict__ cbuf, int E,
    int xTotal, int nbCvt, int nbOut4) {
    __shared__ int cnt[BKT];
    __shared__ int gbase[BKT];
    int b = blockIdx.x;
    int tid = threadIdx.x;
    if (b < 1024) {                        // swizzle_w: 262144 elems
        int i = b * 256 + tid;
        int k  = i >> 12;
        int r  = i & 4095;
        int ni = r >> 10;
        int ks = (r >> 9) & 1;
        int lane = (r >> 3) & 63;
        int j  = r & 7;
        int quad = lane >> 4, l16 = lane & 15;
        int c = ks * 32 + quad * 8 + j;
        int d = ni * 16 + l16;
        swz[i] = __float2bfloat16(w[(k << 12) + (c << 6) + d]);
        return;
    }
    b -= 1024;
    if (b < 16) {                          // swizzle_root: 4096 elems
        int r = b * 256 + tid;
        int ni = r >> 10;
        int ks = (r >> 9) & 1;
        int lane = (r >> 3) & 63;
        int j  = r & 7;
        int quad = lane >> 4, l16 = lane & 15;
        int c = ks * 32 + quad * 8 + j;
        int d = ni * 16 + l16;
        rt[r] = __float2bfloat16(root[(c << 6) + d]);
        return;
    }
    b -= 16;
    if (b < nbCvt) {                       // cvtx: fp32 -> bf16, 8/thread
        int i = (b * 256 + tid) * 8;
        if (i < xTotal) {
            float4 a = *(const float4*)&x[i];
            float4 c = *(const float4*)&x[i + 4];
            uint4 v;
            v.x = pack2bf(a.x, a.y);
            v.y = pack2bf(a.z, a.w);
            v.z = pack2bf(c.x, c.y);
            v.w = pack2bf(c.z, c.w);
            *(uint4*)&xb[i] = v;
        }
        return;
    }
    b -= nbCvt;
    if (b < nbOut4) {                      // initpool, vectorized
        int i = (b * 256 + tid) * 4;
        if (i < outTotal) {
            u32x4 v = {ENC_NEG_INF, ENC_NEG_INF, ENC_NEG_INF, ENC_NEG_INF};
            *(u32x4*)&out[i] = v;
        }
        return;
    }
    b -= nbOut4;
    if (b < (NSLOT * 128) / 256) {         // zero gpart (64*128 floats)
        gpart[b * 256 + tid] = 0.f;
        return;
    }
    b -= (NSLOT * 128) / 256;

    // ---------------- binA (block index b in [0, nbBinA)) ----------------
    if (tid < BKT) cnt[tid] = 0;
    __syncthreads();
    int base = b * 1024 + tid;
    uint2 rr[4]; int bkt4[4], rnk[4]; bool val[4];
#pragma unroll
    for (int i = 0; i < 4; ++i) {
        int e = base + i * 256;
        val[i] = e < E;
        bkt4[i] = 0; rnk[i] = 0;
        if (!val[i]) continue;
        int src = ei[e], dst = ei[E + e];
        float f0 = ea[e * 3 + 0] * 3.f;
        float f1 = ea[e * 3 + 1] * 3.f;
        float f2 = ea[e * 3 + 2] * 3.f;
        float l0 = fminf(fmaxf(floorf(f0), 0.f), 2.f);
        float l1 = fminf(fmaxf(floorf(f1), 0.f), 2.f);
        float l2 = fminf(fmaxf(floorf(f2), 0.f), 2.f);
        unsigned q0 = (unsigned)((f0 - l0) * 1024.f);
        unsigned q1 = (unsigned)((f1 - l1) * 1024.f);
        unsigned q2 = (unsigned)((f2 - l2) * 1024.f);
        int bb = dst >> 9;
        rr[i].x = (unsigned)src | ((unsigned)(int)l0 << 16) |
                  ((unsigned)(int)l1 << 18) | ((unsigned)(int)l2 << 20) | (q2 << 22);
        rr[i].y = q0 | (q1 << 10) | ((unsigned)(dst & 511) << 20);
        bkt4[i] = bb;
        rnk[i] = atomicAdd(&cnt[bb], 1);
    }
    __syncthreads();
    if (tid < BKT) gbase[tid] = cnt[tid] ? atomicAdd(&gcnt[tid], cnt[tid]) : 0;
    __syncthreads();
#pragma unroll
    for (int i = 0; i < 4; ++i) {
        if (!val[i]) continue;
        int pos = gbase[bkt4[i]] + rnk[i];
        if (pos < CAP) cbuf[(size_t)bkt4[i] * CAP + pos] = rr[i];
    }
}

// ---------------------------------------------------------------------------
// Kernel 2: fused binB + root-GEMM + xw-GEMM.
// SCHEDULING LESSON (round 7, confirmed round 9: −4.8us): short blocks FIRST.
//   blocks [0, BKT):            binB — per-bucket dst sort -> CSR
//   blocks [BKT, BKT+nbRoot):   xroot = x @ root -> X buffer (fp32)
//   blocks [.., +1024):         full-channel xw GEMM, kz-plane blocks,
//                               node-major fp8 out, NT 32-KB coop stores
// ---------------------------------------------------------------------------
__global__ __launch_bounds__(256) void gb_kernel(
    const __hip_bfloat16* __restrict__ xb, const __hip_bfloat16* __restrict__ wswz,
    unsigned char* __restrict__ xwc8, int nNodes,
    const uint2* __restrict__ cbuf, const int* __restrict__ gcnt,
    uint2* __restrict__ rec, int* __restrict__ grpoff,
    const __hip_bfloat16* __restrict__ rt, float* __restrict__ X,
    int nbRoot) {
    __shared__ __attribute__((aligned(16))) unsigned char SM[32 * TROW]; // 33.3 KB
    __shared__ int obase_s;

    const int bid = blockIdx.x;
    const int tid = threadIdx.x;

    if (bid < BKT) {
        // ---------------- binB (LDS aliased into SM) ----------------
        int* scnt = (int*)SM;                 // 512 ints
        int* part = (int*)(SM + 2048);        // 256 ints
        const int bkt = bid;

        part[tid] = (tid < bkt) ? gcnt[tid] : 0;
        __syncthreads();
        for (int st = 128; st > 0; st >>= 1) {
            if (tid < st) part[tid] += part[tid + st];
            __syncthreads();
        }
        if (tid == 0) obase_s = part[0];
        __syncthreads();
        int out_base = obase_s;
        int nrec = min(gcnt[bkt], CAP);

        scnt[tid] = 0;
        scnt[256 + tid] = 0;
        __syncthreads();

        const uint2* cb = cbuf + (size_t)bkt * CAP;
        for (int r = tid; r < nrec; r += 256) {
            int lslot = (int)(cb[r].y >> 20) & 511;
            atomicAdd(&scnt[lslot], 1);
        }
        __syncthreads();
        {
            int b2 = tid * 2, s = 0;
#pragma unroll
            for (int i = 0; i < 2; ++i) { int v = scnt[b2 + i]; scnt[b2 + i] = s; s += v; }
            part[tid] = s;
            __syncthreads();
            for (int st = 1; st < 256; st <<= 1) {
                int t2 = (tid >= st) ? part[tid - st] : 0;
                __syncthreads();
                part[tid] += t2;
                __syncthreads();
            }
            int add = (tid == 0) ? 0 : part[tid - 1];
#pragma unroll
            for (int i = 0; i < 2; ++i) scnt[b2 + i] += add;
            __syncthreads();
        }
        int d0 = bkt << 9;
        for (int i = tid; i < 512; i += 256) {
            int d = d0 + i;
            if (d < nNodes) grpoff[d] = out_base + scnt[i];
        }
        if (bkt == BKT - 1 && tid == 0) grpoff[nNodes] = out_base + nrec;
        __syncthreads();
        for (int r = tid; r < nrec; r += 256) {
            uint2 v = cb[r];
            int lslot = (int)(v.y >> 20) & 511;
            int pos = atomicAdd(&scnt[lslot], 1);
            rec[out_base + pos] = v;
        }
        return;
    }

    if (bid < BKT + nbRoot) {
        // ---------------- root GEMM -> X ----------------
        const int rb   = bid - BKT;
        const int wave = tid >> 6, lane = tid & 63;
        const int quad = lane >> 4, l16 = lane & 15;
        const int node = rb * 64 + wave * 16 + l16;
        const bool valid = node < nNodes;

        bf16x8 bf0 = {}, bf1 = {};
        if (valid) {
            const __hip_bfloat16* xp = xb + (size_t)node * CIN + quad * 8;
            bf0 = *(const bf16x8*)(xp);
            bf1 = *(const bf16x8*)(xp + 32);
        }
#pragma unroll
        for (int ni = 0; ni < 4; ++ni) {
            f32x4 acc = {};
            bf16x8 a0 = *(const bf16x8*)&rt[ni * 1024 + 0 * 512 + lane * 8];
            bf16x8 a1 = *(const bf16x8*)&rt[ni * 1024 + 1 * 512 + lane * 8];
            acc = __builtin_amdgcn_mfma_f32_16x16x32_bf16(a0, bf0, acc, 0, 0, 0);
            acc = __builtin_amdgcn_mfma_f32_16x16x32_bf16(a1, bf1, acc, 0, 0, 0);
            if (valid)
                *(f32x4*)&X[(size_t)node * 64 + ni * 16 + quad * 4] = acc;
        }
        return;
    }

    // ---------------- xw GEMM ----------------
    const int gbid = bid - BKT - nbRoot;
    unsigned char* T = SM;
    const int wave = tid >> 6, lane = tid & 63;
    const int quad = lane >> 4, l16 = lane & 15;
    const int kz   = gbid & 3;            // 0..3

    const int tilesTotal = (nNodes + 15) >> 4;
    const int pairsTotal = (tilesTotal + 1) >> 1;

    for (int tp = gbid >> 2; tp < pairsTotal; tp += 256) {
        bf16x8 bf[2][2];
        bf[0][0] = bf16x8{}; bf[0][1] = bf16x8{};
        bf[1][0] = bf16x8{}; bf[1][1] = bf16x8{};
        int nodeA = tp * 32 + l16;
        int nodeB = tp * 32 + 16 + l16;
        if (nodeA < nNodes) {
            const __hip_bfloat16* xp = xb + (size_t)nodeA * CIN + quad * 8;
            bf[0][0] = *(const bf16x8*)(xp);
            bf[0][1] = *(const bf16x8*)(xp + 32);
        }
        if (nodeB < nNodes) {
            const __hip_bfloat16* xp = xb + (size_t)nodeB * CIN + quad * 8;
            bf[1][0] = *(const bf16x8*)(xp);
            bf[1][1] = *(const bf16x8*)(xp + 32);
        }

        for (int k2 = 0; k2 < 4; ++k2) {
            int kloc = (wave << 2) + k2;           // 0..15 within kz-plane
            const __hip_bfloat16* wg = wswz + (size_t)((kz << 4) + kloc) * 4096;
            bf16x8 wf[4][2];
#pragma unroll
            for (int ni = 0; ni < 4; ++ni)
#pragma unroll
                for (int ks = 0; ks < 2; ++ks)
                    wf[ni][ks] = *(const bf16x8*)&wg[ni * 1024 + ks * 512 + lane * 8];
            int xoff = kloc * 64;
#pragma unroll
            for (int t = 0; t < 2; ++t) {
#pragma unroll
                for (int ni = 0; ni < 4; ++ni) {
                    f32x4 acc = {};
                    acc = __builtin_amdgcn_mfma_f32_16x16x32_bf16(wf[ni][0], bf[t][0], acc, 0, 0, 0);
                    acc = __builtin_amdgcn_mfma_f32_16x16x32_bf16(wf[ni][1], bf[t][1], acc, 0, 0, 0);
                    int pk = __builtin_amdgcn_cvt_pk_fp8_f32(acc[0], acc[1], 0, false);
                    pk = __builtin_amdgcn_cvt_pk_fp8_f32(acc[2], acc[3], pk, true);
                    *(unsigned*)&T[(t * 16 + l16) * TROW + xoff + ni * 16 + quad * 4] =
                        (unsigned)pk;
                }
            }
        }
        __syncthreads();
        // NT cooperative store: 32 nodes x 1024 B (keep write stream out of L2)
        int base = tp * 32;
#pragma unroll
        for (int i = 0; i < 8; ++i) {
            int u = i * 256 + tid;          // 16-B unit, 2048 total
            int n = u >> 6, off = u & 63;
            int gn = base + n;
            if (gn < nNodes) {
                u32x4 v = *(const u32x4*)&T[n * TROW + off * 16];
                __builtin_nontemporal_store(
                    v, (u32x4*)&xwc8[(size_t)gn * 4096 + (size_t)kz * 1024 + off * 16]);
            }
        }
        __syncthreads();
    }
}

// ---------------------------------------------------------------------------
// Kernel 3: per-dst aggregation + fused node math. One wave per dst;
// lane = channel. h = elu(acc/deg + xroot + bias) written in place to X.
// BN sums: per-block LDS reduction (grid exact, no early returns), then one
// atomic per partial into 64-way line-spread gpart (1.6M atomics over 512
// lines — round-3 lesson: spread; round-9 lesson: reduce in LDS first,
// device atomics write through to HBM).
// ---------------------------------------------------------------------------
__global__ __launch_bounds__(256) void agg_kernel(
    const uint2* __restrict__ rec, const int* __restrict__ grpoff,
    const unsigned char* __restrict__ xwc8, float* __restrict__ X,
    const float* __restrict__ bias, float* __restrict__ gpart,
    int nNodes) {
    __shared__ float red[8][64];
    int tid  = threadIdx.x;
    int dst  = (blockIdx.x * 256 + tid) >> 6;
    int wave = tid >> 6, lane = tid & 63;

    float hv = 0.f;
    if (dst < nNodes) {
        int lo = __builtin_amdgcn_readfirstlane(grpoff[dst]);
        int hi = __builtin_amdgcn_readfirstlane(grpoff[dst + 1]);

        const float qs = 1.f / 1024.f;
        float acc = 0.f;

        auto corners = [&](uint2 r) {
            int src = (int)(r.x & 0xffffu);
            int l0  = (int)((r.x >> 16) & 3u);
            int l1  = (int)((r.x >> 18) & 3u);
            int l2  = (int)((r.x >> 20) & 3u);
            const unsigned char* p0 =
                xwc8 + (size_t)src * 4096 + l2 * 1024 + (l0 + 4 * l1) * 64 + lane;
            const unsigned char* p1 = p0 + 1024;
            float a00 = __builtin_amdgcn_cvt_f32_fp8((int)p0[0], 0);
            float a10 = __builtin_amdgcn_cvt_f32_fp8((int)p0[64], 0);
            float a01 = __builtin_amdgcn_cvt_f32_fp8((int)p0[256], 0);
            float a11 = __builtin_amdgcn_cvt_f32_fp8((int)p0[320], 0);
            float b00 = __builtin_amdgcn_cvt_f32_fp8((int)p1[0], 0);
            float b10 = __builtin_amdgcn_cvt_f32_fp8((int)p1[64], 0);
            float b01 = __builtin_amdgcn_cvt_f32_fp8((int)p1[256], 0);
            float b11 = __builtin_amdgcn_cvt_f32_fp8((int)p1[320], 0);
            float t0 = (float)(r.y & 1023u) * qs;
            float t1 = (float)((r.y >> 10) & 1023u) * qs;
            float t2 = (float)((r.x >> 22) & 1023u) * qs;
            float u0 = 1.f - t0, u1 = 1.f - t1;
            float w00 = u0 * u1, w10 = t0 * u1, w01 = u0 * t1, w11 = t0 * t1;
            float m0 = w00 * a00 + w10 * a10 + w01 * a01 + w11 * a11;
            float m1 = w00 * b00 + w10 * b10 + w01 * b01 + w11 * b11;
            acc += (1.f - t2) * m0 + t2 * m1;
        };

        int j = lo;
        for (; j + 3 < hi; j += 4) {
            uint2 r0 = rec[j];
            uint2 r1 = rec[j + 1];
            uint2 r2 = rec[j + 2];
            uint2 r3 = rec[j + 3];
            corners(r0);
            corners(r1);
            corners(r2);
            corners(r3);
        }
        for (; j < hi; ++j) corners(rec[j]);

        float deg = fmaxf((float)(hi - lo), 1.f);
        size_t idx = (size_t)dst * COUT + lane;
        float pre = acc / deg + X[idx] + bias[lane];
        hv = pre > 0.f ? pre : expm1f(pre);
        X[idx] = hv;
    }

    red[wave][lane] = hv;
    red[4 + wave][lane] = hv * hv;
    __syncthreads();
    float* gp = gpart + (size_t)(blockIdx.x & (NSLOT - 1)) * 128;
    if (tid < 64) {
        atomicAdd(&gp[tid], red[0][tid] + red[1][tid] + red[2][tid] + red[3][tid]);
    } else if (tid < 128) {
        int d = tid - 64;
        atomicAdd(&gp[64 + d], red[4][d] + red[5][d] + red[6][d] + red[7][d]);
    }
}

// ---------------------------------------------------------------------------
// Kernel 4: fold 64 BN partial slots; emit scale/shift for pool.
// ---------------------------------------------------------------------------
__global__ void stats_kernel(const float* __restrict__ gpart,
                             const float* __restrict__ gamma,
                             const float* __restrict__ beta,
                             float* __restrict__ gstat, int nNodes) {
    __shared__ float sv[128];
    int d = threadIdx.x;                   // 0..127
    float s = 0.f;
    for (int i = 0; i < NSLOT; ++i) s += gpart[i * 128 + d];
    sv[d] = s;
    __syncthreads();
    if (d < 64) {
        float invn = 1.f / (float)nNodes;
        float mean = sv[d] * invn;
        float var  = sv[64 + d] * invn - mean * mean;
        float sc   = gamma[d] * rsqrtf(var + EPSV);
        gstat[d]      = sc;
        gstat[64 + d] = beta[d] - mean * sc;
    }
}

// ---------------------------------------------------------------------------
// Kernel 5: voxel max-pool with precomputed BN scale/shift.
// ---------------------------------------------------------------------------
__global__ __launch_bounds__(256) void pool_kernel(
    const float* __restrict__ h, const float* __restrict__ pos,
    const int* __restrict__ batch, const float* __restrict__ gstat,
    unsigned* __restrict__ out, int nNodes) {
    int gid = blockIdx.x * 256 + threadIdx.x;
    int n = gid >> 6, d = gid & 63;
    if (n >= nNodes) return;
    float v = h[gid] * gstat[d] + gstat[64 + d];
    int v0 = min(max((int)floorf(pos[n * 3 + 0] * (1.f / 32.f)), 0), 7);
    int v1 = min(max((int)floorf(pos[n * 3 + 1] * (1.f / 32.f)), 0), 7);
    int v2 = min(max((int)floorf(pos[n * 3 + 2] * (1.f / 32.f)), 0), 7);
    int cl = batch[n] * 512 + v0 * 64 + v1 * 8 + v2;
    atomicMax(&out[cl * 64 + d], encf(v));
}

__global__ __launch_bounds__(256) void decode_kernel(unsigned* __restrict__ out, int total) {
    int i = blockIdx.x * 256 + threadIdx.x;
    if (i >= total) return;
    float f = decf(out[i]);
    if (!isfinite(f)) f = 0.f;
    ((float*)out)[i] = f;
}

// ---------------------------------------------------------------------------
extern "C" void kernel_launch(void* const* d_in, const int* in_sizes, int n_in,
                              void* d_out, int out_size, void* d_ws, size_t ws_size,
                              hipStream_t stream) {
    const float* x     = (const float*)d_in[0];
    const int*   ei    = (const int*)d_in[1];
    const float* ea    = (const float*)d_in[2];
    const float* pos   = (const float*)d_in[3];
    const int*   batch = (const int*)d_in[4];
    const float* w     = (const float*)d_in[5];
    const float* root  = (const float*)d_in[6];
    const float* bias  = (const float*)d_in[7];
    const float* gamma = (const float*)d_in[8];
    const float* beta  = (const float*)d_in[9];

    const int N = in_sizes[0] / CIN;     // 50000
    const int E = in_sizes[1] / 2;       // 800000

    // workspace carve-up (~239 MB); X holds xroot then h in place
    char* ws = (char*)d_ws;
    size_t off_b = 0;
    auto carve = [&](size_t bytes) -> char* {
        char* p = ws + off_b;
        off_b = (off_b + bytes + 255) & ~(size_t)255;
        return p;
    };
    unsigned char*  xwc8   = (unsigned char*)carve((size_t)N * NK * COUT);    // 204.8 MB
    __hip_bfloat16* wt     = (__hip_bfloat16*)carve((size_t)(NK + 1) * CIN * COUT * 2);
    __hip_bfloat16* xb     = (__hip_bfloat16*)carve((size_t)N * CIN * 2);     // 6.4 MB
    float*          X      = (float*)carve((size_t)N * COUT * 4);             // 12.8 MB
    int*            grpoff = (int*)carve((size_t)(N + 1) * 4);
    int*            gcnt   = (int*)carve(BKT * 4);
    uint2*          cbuf   = (uint2*)carve((size_t)BKT * CAP * 8);            // 7.6 MB
    uint2*          rec    = (uint2*)carve((size_t)E * 8);                    // 6.4 MB
    float*          gst    = (float*)carve(256 * 4);
    float*          gpart  = (float*)carve((size_t)NSLOT * 128 * 4);          // 32 KB
    __hip_bfloat16* rt     = wt + (size_t)NK * CIN * COUT;

    // 0: stream-ordered zeroing of counters consumed WITHIN the next launch
    hipMemsetAsync(gcnt, 0, BKT * 4, stream);

    // 1: fused prep (swizzles + cvtx + pool-init + gpart zero) + binA
    const int nbCvt  = (N * CIN / 8 + 255) / 256;
    const int nbOut4 = (out_size / 4 + 255) / 256;
    const int nbBinA = (E + 1023) / 1024;
    const int nbGpz  = (NSLOT * 128) / 256;
    prep_kernel<<<1024 + 16 + nbCvt + nbOut4 + nbGpz + nbBinA, 256, 0, stream>>>(
        w, wt, root, rt, x, xb, (unsigned*)d_out, out_size, gcnt, gpart,
        ei, ea, cbuf, E, N * CIN, nbCvt, nbOut4);

    // 2: fused binB + root-GEMM + xw-GEMM (short blocks FIRST)
    const int nbRoot = (N + 63) / 64;
    gb_kernel<<<BKT + nbRoot + 1024, 256, 0, stream>>>(
        xb, wt, xwc8, N, cbuf, gcnt, rec, grpoff, rt, X, nbRoot);

    // 3: per-dst aggregation + fused ELU + block-reduced BN partials
    const int agrid = (N * 64 + 255) / 256;
    agg_kernel<<<agrid, 256, 0, stream>>>(
        rec, grpoff, xwc8, X, bias, gpart, N);

    // 4: fold BN partials -> scale/shift
    stats_kernel<<<1, 128, 0, stream>>>(gpart, gamma, beta, gst, N);

    // 5: BN affine + voxel max-pool
    pool_kernel<<<((size_t)N * COUT + 255) / 256, 256, 0, stream>>>(
        X, pos, batch, gst, (unsigned*)d_out, N);

    // 6: decode sortable-uint -> float
    decode_kernel<<<(out_size + 255) / 256, 256, 0, stream>>>((unsigned*)d_out, out_size);
}

// Round 11
// 264.982 us; speedup vs baseline: 1.0301x; 1.0083x over previous
//
#include <hip/hip_runtime.h>
#include <hip/hip_bf16.h>

typedef __attribute__((ext_vector_type(8))) short bf16x8;
typedef __attribute__((ext_vector_type(4))) float f32x4;
typedef __attribute__((ext_vector_type(4))) unsigned int u32x4;

#define CIN 64
#define COUT 64
#define NK 64
#define EPSV 1e-5f
#define ENC_NEG_INF 0x007FFFFFu
#define BKT 98               // coarse buckets = ceil(50000/512)
#define CAP 9728             // records per bucket (mean 8163)
#define TROW 1024            // LDS row bytes; XOR swizzle replaces pad -> 32KB, 5 blk/CU
#define NSLOT 64             // BN partial-sum spread slots (64 x 128 floats)

__device__ __forceinline__ unsigned encf(float f) {
    unsigned b = __float_as_uint(f);
    return (b & 0x80000000u) ? ~b : (b | 0x80000000u);
}
__device__ __forceinline__ float decf(unsigned u) {
    unsigned b = (u & 0x80000000u) ? (u & 0x7FFFFFFFu) : ~u;
    return __uint_as_float(b);
}
__device__ __forceinline__ unsigned pack2bf(float a, float b) {
    unsigned ua = (unsigned)__bfloat16_as_ushort(__float2bfloat16(a));
    unsigned ub = (unsigned)__bfloat16_as_ushort(__float2bfloat16(b));
    return ua | (ub << 16);
}

// ---------------------------------------------------------------------------
// Kernel 1: fused prep + binA.
// RACE LESSON (round 5): gcnt is consumed by binA blocks IN THIS LAUNCH ->
// zeroed by hipMemsetAsync BEFORE this launch. gpart is consumed only by
// LATER launches, so zeroing it in-grid is safe.
// FENCE LESSON (round 6): no per-block __threadfence tickets on CDNA4.
// ATOMIC LESSON (round 9): device atomics write through toward HBM — use
// per-block LDS reduction first (1.6M atomics, not 6.4M).
// rec: x = src(16) | l0<<16 | l1<<18 | l2<<20 | q2<<22
//      y = q0 (10) | q1<<10 (10) | lslot<<20 (9; lslot = dst&511)
// ---------------------------------------------------------------------------
__global__ __launch_bounds__(256) void prep_kernel(
    const float* __restrict__ w, __hip_bfloat16* __restrict__ swz,
    const float* __restrict__ root, __hip_bfloat16* __restrict__ rt,
    const float* __restrict__ x, __hip_bfloat16* __restrict__ xb,
    unsigned* __restrict__ out, int outTotal,
    int* __restrict__ gcnt, float* __restrict__ gpart,
    const int* __restrict__ ei, const float* __restrict__ ea,
    uint2* __restrict__ cbuf, int E,
    int xTotal, int nbCvt, int nbOut4) {
    __shared__ int cnt[BKT];
    __shared__ int gbase[BKT];
    int b = blockIdx.x;
    int tid = threadIdx.x;
    if (b < 1024) {                        // swizzle_w: 262144 elems
        int i = b * 256 + tid;
        int k  = i >> 12;
        int r  = i & 4095;
        int ni = r >> 10;
        int ks = (r >> 9) & 1;
        int lane = (r >> 3) & 63;
        int j  = r & 7;
        int quad = lane >> 4, l16 = lane & 15;
        int c = ks * 32 + quad * 8 + j;
        int d = ni * 16 + l16;
        swz[i] = __float2bfloat16(w[(k << 12) + (c << 6) + d]);
        return;
    }
    b -= 1024;
    if (b < 16) {                          // swizzle_root: 4096 elems
        int r = b * 256 + tid;
        int ni = r >> 10;
        int ks = (r >> 9) & 1;
        int lane = (r >> 3) & 63;
        int j  = r & 7;
        int quad = lane >> 4, l16 = lane & 15;
        int c = ks * 32 + quad * 8 + j;
        int d = ni * 16 + l16;
        rt[r] = __float2bfloat16(root[(c << 6) + d]);
        return;
    }
    b -= 16;
    if (b < nbCvt) {                       // cvtx: fp32 -> bf16, 8/thread
        int i = (b * 256 + tid) * 8;
        if (i < xTotal) {
            float4 a = *(const float4*)&x[i];
            float4 c = *(const float4*)&x[i + 4];
            uint4 v;
            v.x = pack2bf(a.x, a.y);
            v.y = pack2bf(a.z, a.w);
            v.z = pack2bf(c.x, c.y);
            v.w = pack2bf(c.z, c.w);
            *(uint4*)&xb[i] = v;
        }
        return;
    }
    b -= nbCvt;
    if (b < nbOut4) {                      // initpool, vectorized
        int i = (b * 256 + tid) * 4;
        if (i < outTotal) {
            u32x4 v = {ENC_NEG_INF, ENC_NEG_INF, ENC_NEG_INF, ENC_NEG_INF};
            *(u32x4*)&out[i] = v;
        }
        return;
    }
    b -= nbOut4;
    if (b < (NSLOT * 128) / 256) {         // zero gpart (64*128 floats)
        gpart[b * 256 + tid] = 0.f;
        return;
    }
    b -= (NSLOT * 128) / 256;

    // ---------------- binA (block index b in [0, nbBinA)) ----------------
    if (tid < BKT) cnt[tid] = 0;
    __syncthreads();
    int base = b * 1024 + tid;
    uint2 rr[4]; int bkt4[4], rnk[4]; bool val[4];
#pragma unroll
    for (int i = 0; i < 4; ++i) {
        int e = base + i * 256;
        val[i] = e < E;
        bkt4[i] = 0; rnk[i] = 0;
        if (!val[i]) continue;
        int src = ei[e], dst = ei[E + e];
        float f0 = ea[e * 3 + 0] * 3.f;
        float f1 = ea[e * 3 + 1] * 3.f;
        float f2 = ea[e * 3 + 2] * 3.f;
        float l0 = fminf(fmaxf(floorf(f0), 0.f), 2.f);
        float l1 = fminf(fmaxf(floorf(f1), 0.f), 2.f);
        float l2 = fminf(fmaxf(floorf(f2), 0.f), 2.f);
        unsigned q0 = (unsigned)((f0 - l0) * 1024.f);
        unsigned q1 = (unsigned)((f1 - l1) * 1024.f);
        unsigned q2 = (unsigned)((f2 - l2) * 1024.f);
        int bb = dst >> 9;
        rr[i].x = (unsigned)src | ((unsigned)(int)l0 << 16) |
                  ((unsigned)(int)l1 << 18) | ((unsigned)(int)l2 << 20) | (q2 << 22);
        rr[i].y = q0 | (q1 << 10) | ((unsigned)(dst & 511) << 20);
        bkt4[i] = bb;
        rnk[i] = atomicAdd(&cnt[bb], 1);
    }
    __syncthreads();
    if (tid < BKT) gbase[tid] = cnt[tid] ? atomicAdd(&gcnt[tid], cnt[tid]) : 0;
    __syncthreads();
#pragma unroll
    for (int i = 0; i < 4; ++i) {
        if (!val[i]) continue;
        int pos = gbase[bkt4[i]] + rnk[i];
        if (pos < CAP) cbuf[(size_t)bkt4[i] * CAP + pos] = rr[i];
    }
}

// ---------------------------------------------------------------------------
// Kernel 2: fused binB + root-GEMM + xw-GEMM.
// SCHEDULING LESSON (round 7): short blocks FIRST in the grid.
// LDS: 32 KB exactly (XOR swizzle replaces the +16 row pad) -> 5 blocks/CU
// instead of 4. Swizzle: logical byte c of row r stored at c ^ ((r&7)<<4);
// MFMA-phase 4B writes spread over 8 banks (2-way = free, m136); coop read
// stays 16B-contiguous per lane with a permuted unit index.
//   blocks [0, BKT):            binB — per-bucket dst sort -> CSR
//   blocks [BKT, BKT+nbRoot):   xroot = x @ root -> X buffer (fp32)
//   blocks [.., +1024):         full-channel xw GEMM, node-major fp8 out
// ---------------------------------------------------------------------------
__global__ __launch_bounds__(256) void gb_kernel(
    const __hip_bfloat16* __restrict__ xb, const __hip_bfloat16* __restrict__ wswz,
    unsigned char* __restrict__ xwc8, int nNodes,
    const uint2* __restrict__ cbuf, const int* __restrict__ gcnt,
    uint2* __restrict__ rec, int* __restrict__ grpoff,
    const __hip_bfloat16* __restrict__ rt, float* __restrict__ X,
    int nbRoot) {
    __shared__ __attribute__((aligned(16))) unsigned char SM[32 * TROW]; // 32 KB
    __shared__ int obase_s;

    const int bid = blockIdx.x;
    const int tid = threadIdx.x;

    if (bid < BKT) {
        // ---------------- binB (LDS aliased into SM) ----------------
        int* scnt = (int*)SM;                 // 512 ints
        int* part = (int*)(SM + 2048);        // 256 ints
        const int bkt = bid;

        part[tid] = (tid < bkt) ? gcnt[tid] : 0;
        __syncthreads();
        for (int st = 128; st > 0; st >>= 1) {
            if (tid < st) part[tid] += part[tid + st];
            __syncthreads();
        }
        if (tid == 0) obase_s = part[0];
        __syncthreads();
        int out_base = obase_s;
        int nrec = min(gcnt[bkt], CAP);

        scnt[tid] = 0;
        scnt[256 + tid] = 0;
        __syncthreads();

        const uint2* cb = cbuf + (size_t)bkt * CAP;
        for (int r = tid; r < nrec; r += 256) {
            int lslot = (int)(cb[r].y >> 20) & 511;
            atomicAdd(&scnt[lslot], 1);
        }
        __syncthreads();
        {
            int b2 = tid * 2, s = 0;
#pragma unroll
            for (int i = 0; i < 2; ++i) { int v = scnt[b2 + i]; scnt[b2 + i] = s; s += v; }
            part[tid] = s;
            __syncthreads();
            for (int st = 1; st < 256; st <<= 1) {
                int t2 = (tid >= st) ? part[tid - st] : 0;
                __syncthreads();
                part[tid] += t2;
                __syncthreads();
            }
            int add = (tid == 0) ? 0 : part[tid - 1];
#pragma unroll
            for (int i = 0; i < 2; ++i) scnt[b2 + i] += add;
            __syncthreads();
        }
        int d0 = bkt << 9;
        for (int i = tid; i < 512; i += 256) {
            int d = d0 + i;
            if (d < nNodes) grpoff[d] = out_base + scnt[i];
        }
        if (bkt == BKT - 1 && tid == 0) grpoff[nNodes] = out_base + nrec;
        __syncthreads();
        for (int r = tid; r < nrec; r += 256) {
            uint2 v = cb[r];
            int lslot = (int)(v.y >> 20) & 511;
            int pos = atomicAdd(&scnt[lslot], 1);
            rec[out_base + pos] = v;
        }
        return;
    }

    if (bid < BKT + nbRoot) {
        // ---------------- root GEMM -> X ----------------
        const int rb   = bid - BKT;
        const int wave = tid >> 6, lane = tid & 63;
        const int quad = lane >> 4, l16 = lane & 15;
        const int node = rb * 64 + wave * 16 + l16;
        const bool valid = node < nNodes;

        bf16x8 bf0 = {}, bf1 = {};
        if (valid) {
            const __hip_bfloat16* xp = xb + (size_t)node * CIN + quad * 8;
            bf0 = *(const bf16x8*)(xp);
            bf1 = *(const bf16x8*)(xp + 32);
        }
#pragma unroll
        for (int ni = 0; ni < 4; ++ni) {
            f32x4 acc = {};
            bf16x8 a0 = *(const bf16x8*)&rt[ni * 1024 + 0 * 512 + lane * 8];
            bf16x8 a1 = *(const bf16x8*)&rt[ni * 1024 + 1 * 512 + lane * 8];
            acc = __builtin_amdgcn_mfma_f32_16x16x32_bf16(a0, bf0, acc, 0, 0, 0);
            acc = __builtin_amdgcn_mfma_f32_16x16x32_bf16(a1, bf1, acc, 0, 0, 0);
            if (valid)
                *(f32x4*)&X[(size_t)node * 64 + ni * 16 + quad * 4] = acc;
        }
        return;
    }

    // ---------------- xw GEMM ----------------
    const int gbid = bid - BKT - nbRoot;
    unsigned char* T = SM;
    const int wave = tid >> 6, lane = tid & 63;
    const int quad = lane >> 4, l16 = lane & 15;
    const int kz   = gbid & 3;            // 0..3

    const int tilesTotal = (nNodes + 15) >> 4;
    const int pairsTotal = (tilesTotal + 1) >> 1;

    for (int tp = gbid >> 2; tp < pairsTotal; tp += 256) {
        bf16x8 bf[2][2];
        bf[0][0] = bf16x8{}; bf[0][1] = bf16x8{};
        bf[1][0] = bf16x8{}; bf[1][1] = bf16x8{};
        int nodeA = tp * 32 + l16;
        int nodeB = tp * 32 + 16 + l16;
        if (nodeA < nNodes) {
            const __hip_bfloat16* xp = xb + (size_t)nodeA * CIN + quad * 8;
            bf[0][0] = *(const bf16x8*)(xp);
            bf[0][1] = *(const bf16x8*)(xp + 32);
        }
        if (nodeB < nNodes) {
            const __hip_bfloat16* xp = xb + (size_t)nodeB * CIN + quad * 8;
            bf[1][0] = *(const bf16x8*)(xp);
            bf[1][1] = *(const bf16x8*)(xp + 32);
        }

        for (int k2 = 0; k2 < 4; ++k2) {
            int kloc = (wave << 2) + k2;           // 0..15 within kz-plane
            const __hip_bfloat16* wg = wswz + (size_t)((kz << 4) + kloc) * 4096;
            bf16x8 wf[4][2];
#pragma unroll
            for (int ni = 0; ni < 4; ++ni)
#pragma unroll
                for (int ks = 0; ks < 2; ++ks)
                    wf[ni][ks] = *(const bf16x8*)&wg[ni * 1024 + ks * 512 + lane * 8];
            int xoff = kloc * 64;
#pragma unroll
            for (int t = 0; t < 2; ++t) {
                int row = t * 16 + l16;
                int rsw = (row & 7) << 4;          // XOR swizzle bits 4-6
#pragma unroll
                for (int ni = 0; ni < 4; ++ni) {
                    f32x4 acc = {};
                    acc = __builtin_amdgcn_mfma_f32_16x16x32_bf16(wf[ni][0], bf[t][0], acc, 0, 0, 0);
                    acc = __builtin_amdgcn_mfma_f32_16x16x32_bf16(wf[ni][1], bf[t][1], acc, 0, 0, 0);
                    int pk = __builtin_amdgcn_cvt_pk_fp8_f32(acc[0], acc[1], 0, false);
                    pk = __builtin_amdgcn_cvt_pk_fp8_f32(acc[2], acc[3], pk, true);
                    int c = xoff + ni * 16 + quad * 4;
                    *(unsigned*)&T[row * TROW + (c ^ rsw)] = (unsigned)pk;
                }
            }
        }
        __syncthreads();
        // cooperative store: 32 nodes x 1024 B; read uses the inverse swizzle
        int base = tp * 32;
#pragma unroll
        for (int i = 0; i < 8; ++i) {
            int u = i * 256 + tid;          // 16-B unit, 2048 total
            int n = u >> 6, off = u & 63;
            int gn = base + n;
            if (gn < nNodes) {
                u32x4 v = *(const u32x4*)&T[n * TROW + ((off ^ (n & 7)) * 16)];
                *(u32x4*)&xwc8[(size_t)gn * 4096 + (size_t)kz * 1024 + off * 16] = v;
            }
        }
        __syncthreads();
    }
}

// ---------------------------------------------------------------------------
// Kernel 3: per-dst aggregation + fused node math. One wave per dst;
// lane = channel. h = elu(acc/deg + xroot + bias) written in place to X.
// BN sums: per-block LDS reduction (grid exact, no early returns), then one
// atomic per partial into 64-way line-spread gpart (1.6M atomics over 512
// lines — round-3 lesson: spread; round-9 lesson: reduce in LDS first).
// ---------------------------------------------------------------------------
__global__ __launch_bounds__(256) void agg_kernel(
    const uint2* __restrict__ rec, const int* __restrict__ grpoff,
    const unsigned char* __restrict__ xwc8, float* __restrict__ X,
    const float* __restrict__ bias, float* __restrict__ gpart,
    int nNodes) {
    __shared__ float red[8][64];
    int tid  = threadIdx.x;
    int dst  = (blockIdx.x * 256 + tid) >> 6;
    int wave = tid >> 6, lane = tid & 63;

    float hv = 0.f;
    if (dst < nNodes) {
        int lo = __builtin_amdgcn_readfirstlane(grpoff[dst]);
        int hi = __builtin_amdgcn_readfirstlane(grpoff[dst + 1]);

        const float qs = 1.f / 1024.f;
        float acc = 0.f;

        auto corners = [&](uint2 r) {
            int src = (int)(r.x & 0xffffu);
            int l0  = (int)((r.x >> 16) & 3u);
            int l1  = (int)((r.x >> 18) & 3u);
            int l2  = (int)((r.x >> 20) & 3u);
            const unsigned char* p0 =
                xwc8 + (size_t)src * 4096 + l2 * 1024 + (l0 + 4 * l1) * 64 + lane;
            const unsigned char* p1 = p0 + 1024;
            float a00 = __builtin_amdgcn_cvt_f32_fp8((int)p0[0], 0);
            float a10 = __builtin_amdgcn_cvt_f32_fp8((int)p0[64], 0);
            float a01 = __builtin_amdgcn_cvt_f32_fp8((int)p0[256], 0);
            float a11 = __builtin_amdgcn_cvt_f32_fp8((int)p0[320], 0);
            float b00 = __builtin_amdgcn_cvt_f32_fp8((int)p1[0], 0);
            float b10 = __builtin_amdgcn_cvt_f32_fp8((int)p1[64], 0);
            float b01 = __builtin_amdgcn_cvt_f32_fp8((int)p1[256], 0);
            float b11 = __builtin_amdgcn_cvt_f32_fp8((int)p1[320], 0);
            float t0 = (float)(r.y & 1023u) * qs;
            float t1 = (float)((r.y >> 10) & 1023u) * qs;
            float t2 = (float)((r.x >> 22) & 1023u) * qs;
            float u0 = 1.f - t0, u1 = 1.f - t1;
            float w00 = u0 * u1, w10 = t0 * u1, w01 = u0 * t1, w11 = t0 * t1;
            float m0 = w00 * a00 + w10 * a10 + w01 * a01 + w11 * a11;
            float m1 = w00 * b00 + w10 * b10 + w01 * b01 + w11 * b11;
            acc += (1.f - t2) * m0 + t2 * m1;
        };

        int j = lo;
        for (; j + 3 < hi; j += 4) {
            uint2 r0 = rec[j];
            uint2 r1 = rec[j + 1];
            uint2 r2 = rec[j + 2];
            uint2 r3 = rec[j + 3];
            corners(r0);
            corners(r1);
            corners(r2);
            corners(r3);
        }
        for (; j < hi; ++j) corners(rec[j]);

        float deg = fmaxf((float)(hi - lo), 1.f);
        size_t idx = (size_t)dst * COUT + lane;
        float pre = acc / deg + X[idx] + bias[lane];
        hv = pre > 0.f ? pre : expm1f(pre);
        X[idx] = hv;
    }

    red[wave][lane] = hv;
    red[4 + wave][lane] = hv * hv;
    __syncthreads();
    float* gp = gpart + (size_t)(blockIdx.x & (NSLOT - 1)) * 128;
    if (tid < 64) {
        atomicAdd(&gp[tid], red[0][tid] + red[1][tid] + red[2][tid] + red[3][tid]);
    } else if (tid < 128) {
        int d = tid - 64;
        atomicAdd(&gp[64 + d], red[4][d] + red[5][d] + red[6][d] + red[7][d]);
    }
}

// ---------------------------------------------------------------------------
// Kernel 4: fold 64 BN partial slots; emit scale/shift for pool.
// ---------------------------------------------------------------------------
__global__ void stats_kernel(const float* __restrict__ gpart,
                             const float* __restrict__ gamma,
                             const float* __restrict__ beta,
                             float* __restrict__ gstat, int nNodes) {
    __shared__ float sv[128];
    int d = threadIdx.x;                   // 0..127
    float s = 0.f;
    for (int i = 0; i < NSLOT; ++i) s += gpart[i * 128 + d];
    sv[d] = s;
    __syncthreads();
    if (d < 64) {
        float invn = 1.f / (float)nNodes;
        float mean = sv[d] * invn;
        float var  = sv[64 + d] * invn - mean * mean;
        float sc   = gamma[d] * rsqrtf(var + EPSV);
        gstat[d]      = sc;
        gstat[64 + d] = beta[d] - mean * sc;
    }
}

// ---------------------------------------------------------------------------
// Kernel 5: voxel max-pool with precomputed BN scale/shift.
// ---------------------------------------------------------------------------
__global__ __launch_bounds__(256) void pool_kernel(
    const float* __restrict__ h, const float* __restrict__ pos,
    const int* __restrict__ batch, const float* __restrict__ gstat,
    unsigned* __restrict__ out, int nNodes) {
    int gid = blockIdx.x * 256 + threadIdx.x;
    int n = gid >> 6, d = gid & 63;
    if (n >= nNodes) return;
    float v = h[gid] * gstat[d] + gstat[64 + d];
    int v0 = min(max((int)floorf(pos[n * 3 + 0] * (1.f / 32.f)), 0), 7);
    int v1 = min(max((int)floorf(pos[n * 3 + 1] * (1.f / 32.f)), 0), 7);
    int v2 = min(max((int)floorf(pos[n * 3 + 2] * (1.f / 32.f)), 0), 7);
    int cl = batch[n] * 512 + v0 * 64 + v1 * 8 + v2;
    atomicMax(&out[cl * 64 + d], encf(v));
}

__global__ __launch_bounds__(256) void decode_kernel(unsigned* __restrict__ out, int total) {
    int i = blockIdx.x * 256 + threadIdx.x;
    if (i >= total) return;
    float f = decf(out[i]);
    if (!isfinite(f)) f = 0.f;
    ((float*)out)[i] = f;
}

// ---------------------------------------------------------------------------
extern "C" void kernel_launch(void* const* d_in, const int* in_sizes, int n_in,
                              void* d_out, int out_size, void* d_ws, size_t ws_size,
                              hipStream_t stream) {
    const float* x     = (const float*)d_in[0];
    const int*   ei    = (const int*)d_in[1];
    const float* ea    = (const float*)d_in[2];
    const float* pos   = (const float*)d_in[3];
    const int*   batch = (const int*)d_in[4];
    const float* w     = (const float*)d_in[5];
    const float* root  = (const float*)d_in[6];
    const float* bias  = (const float*)d_in[7];
    const float* gamma = (const float*)d_in[8];
    const float* beta  = (const float*)d_in[9];

    const int N = in_sizes[0] / CIN;     // 50000
    const int E = in_sizes[1] / 2;       // 800000

    // workspace carve-up (~239 MB); X holds xroot then h in place
    char* ws = (char*)d_ws;
    size_t off_b = 0;
    auto carve = [&](size_t bytes) -> char* {
        char* p = ws + off_b;
        off_b = (off_b + bytes + 255) & ~(size_t)255;
        return p;
    };
    unsigned char*  xwc8   = (unsigned char*)carve((size_t)N * NK * COUT);    // 204.8 MB
    __hip_bfloat16* wt     = (__hip_bfloat16*)carve((size_t)(NK + 1) * CIN * COUT * 2);
    __hip_bfloat16* xb     = (__hip_bfloat16*)carve((size_t)N * CIN * 2);     // 6.4 MB
    float*          X      = (float*)carve((size_t)N * COUT * 4);             // 12.8 MB
    int*            grpoff = (int*)carve((size_t)(N + 1) * 4);
    int*            gcnt   = (int*)carve(BKT * 4);
    uint2*          cbuf   = (uint2*)carve((size_t)BKT * CAP * 8);            // 7.6 MB
    uint2*          rec    = (uint2*)carve((size_t)E * 8);                    // 6.4 MB
    float*          gst    = (float*)carve(256 * 4);
    float*          gpart  = (float*)carve((size_t)NSLOT * 128 * 4);          // 32 KB
    __hip_bfloat16* rt     = wt + (size_t)NK * CIN * COUT;

    // 0: stream-ordered zeroing of counters consumed WITHIN the next launch
    hipMemsetAsync(gcnt, 0, BKT * 4, stream);

    // 1: fused prep (swizzles + cvtx + pool-init + gpart zero) + binA
    const int nbCvt  = (N * CIN / 8 + 255) / 256;
    const int nbOut4 = (out_size / 4 + 255) / 256;
    const int nbBinA = (E + 1023) / 1024;
    const int nbGpz  = (NSLOT * 128) / 256;
    prep_kernel<<<1024 + 16 + nbCvt + nbOut4 + nbGpz + nbBinA, 256, 0, stream>>>(
        w, wt, root, rt, x, xb, (unsigned*)d_out, out_size, gcnt, gpart,
        ei, ea, cbuf, E, N * CIN, nbCvt, nbOut4);

    // 2: fused binB + root-GEMM + xw-GEMM (short blocks FIRST)
    const int nbRoot = (N + 63) / 64;
    gb_kernel<<<BKT + nbRoot + 1024, 256, 0, stream>>>(
        xb, wt, xwc8, N, cbuf, gcnt, rec, grpoff, rt, X, nbRoot);

    // 3: per-dst aggregation + fused ELU + block-reduced BN partials
    const int agrid = (N * 64 + 255) / 256;
    agg_kernel<<<agrid, 256, 0, stream>>>(
        rec, grpoff, xwc8, X, bias, gpart, N);

    // 4: fold BN partials -> scale/shift
    stats_kernel<<<1, 128, 0, stream>>>(gpart, gamma, beta, gst, N);

    // 5: BN affine + voxel max-pool
    pool_kernel<<<((size_t)N * COUT + 255) / 256, 256, 0, stream>>>(
        X, pos, batch, gst, (unsigned*)d_out, N);

    // 6: decode sortable-uint -> float
    decode_kernel<<<(out_size + 255) / 256, 256, 0, stream>>>((unsigned*)d_out, out_size);
}